// Round 2
// baseline (326.044 us; speedup 1.0000x reference)
//
#include <hip/hip_runtime.h>
#include <hip/hip_bf16.h>

#define BN1 160
#define BN2 1024
#define BD  256

#define GB_F     0.0036f
#define INV_GB_F (1.0f / 0.0036f)

// Precomputed sigmoid offsets (rewritten every launch; no d_ws dependency).
__device__ float g_z1min[BN1 * BD];
__device__ float g_z1max[BN1 * BD];
__device__ float g_z2min[BN2 * BD];
__device__ float g_z2max[BN2 * BD];

__device__ __forceinline__ float softplus10(float x) {
    // softplus(10x)/10, stable: (max(y,0) + log1p(exp(-|y|))) / 10
    float y = 10.0f * x;
    float t = __expf(-fabsf(y));
    return (fmaxf(y, 0.0f) + __logf(1.0f + t)) * 0.1f;
}

__device__ __forceinline__ float sigmoidf(float x) {
    return 1.0f / (1.0f + __expf(-x));
}

__global__ __launch_bounds__(256) void precompute_kernel(
        const float* __restrict__ box1s, const float* __restrict__ box2s) {
    int idx = blockIdx.x * 256 + threadIdx.x;
    if (idx < BN2 * BD) {
        int n = idx >> 8;          // / BD
        int d = idx & (BD - 1);    // % BD
        float c  = box2s[n * 2 * BD + d];
        float sp = softplus10(box2s[n * 2 * BD + BD + d]);
        g_z2min[idx] = sigmoidf(c - sp);
        g_z2max[idx] = sigmoidf(c + sp);
    } else {
        int j = idx - BN2 * BD;
        if (j < BN1 * BD) {
            int n = j >> 8;
            int d = j & (BD - 1);
            float c  = box1s[n * 2 * BD + d];
            float sp = softplus10(box1s[n * 2 * BD + BD + d]);
            g_z1min[j] = sigmoidf(c - sp);
            g_z1max[j] = sigmoidf(c + sp);
        }
    }
}

union F4 {
    float4 v;
    float f[4];
};

// 4 rows per block (row = i2*BN1 + i1), 64 lanes per row, 4 d per lane.
// Each wave's float4 store covers one full 1 KiB contiguous row segment.
__global__ __launch_bounds__(256) void pairs_kernel(float* __restrict__ out) {
    const int t    = threadIdx.x;
    const int row  = blockIdx.x * 4 + (t >> 6);   // row = i2*BN1 + i1
    const int d0   = (t & 63) << 2;

    const int i2 = row / BN1;
    const int i1 = row - i2 * BN1;

    F4 a, A, b, B;
    a.v = *(const float4*)(g_z2min + i2 * BD + d0);
    A.v = *(const float4*)(g_z2max + i2 * BD + d0);
    b.v = *(const float4*)(g_z1min + i1 * BD + d0);
    B.v = *(const float4*)(g_z1max + i1 * BD + d0);

    F4 o0, o1;
#pragma unroll
    for (int j = 0; j < 4; ++j) {
        float av = a.f[j], bv = b.f[j];
        float m  = fmaxf(av, bv);
        float c0 = GB_F * __logf(1.0f + __expf(-fabsf(av - bv) * INV_GB_F));
        o0.f[j]  = fmaxf(m + c0, m);   // inter_min

        float Av = A.f[j], Bv = B.f[j];
        float M  = fminf(Av, Bv);
        float c1 = GB_F * __logf(1.0f + __expf(-fabsf(Av - Bv) * INV_GB_F));
        o1.f[j]  = fminf(M - c1, M);   // inter_max
    }

    const size_t base = (size_t)row * BD + d0;
    const size_t half = (size_t)BN2 * BN1 * BD;
    *(float4*)(out + base)        = o0.v;
    *(float4*)(out + half + base) = o1.v;
}

extern "C" void kernel_launch(void* const* d_in, const int* in_sizes, int n_in,
                              void* d_out, int out_size, void* d_ws, size_t ws_size,
                              hipStream_t stream) {
    const float* box1s = (const float*)d_in[0];
    const float* box2s = (const float*)d_in[1];
    float* out = (float*)d_out;

    // (BN2*BD + BN1*BD) = 303104 elements = exactly 1184 blocks of 256
    precompute_kernel<<<1184, 256, 0, stream>>>(box1s, box2s);

    // BN2*BN1 rows / 4 rows per block
    pairs_kernel<<<(BN2 * BN1) / 4, 256, 0, stream>>>(out);
}